// Round 2
// baseline (220.561 us; speedup 1.0000x reference)
//
#include <hip/hip_runtime.h>
#include <cstdint>
#include <cstddef>

// Problem constants
#define B_SZ   64
#define IN_CH  32
#define OUT_CH 32
#define NMAPS  64
#define HW     4096          // 64*64
#define CTRLN  512
#define NROWS  4160          // NF(64) + NI(2048) + NO(2048)
#define OUT0_SZ (B_SZ*OUT_CH*HW)
#define TILE   128

typedef short bf8_t  __attribute__((ext_vector_type(8)));   // 8 bf16 = 4 VGPR
typedef short bf4_t  __attribute__((ext_vector_type(4)));   // 4 bf16 = 2 VGPR
typedef float f32x4  __attribute__((ext_vector_type(4)));

__device__ __forceinline__ unsigned short f2bf(float f) {
    union { float f; uint32_t u; } v; v.f = f;
    return (unsigned short)((v.u + 0x7FFFu + ((v.u >> 16) & 1u)) >> 16);  // RNE
}
__device__ __forceinline__ float bf2f(unsigned short h) {
    union { uint32_t u; float f; } v; v.u = (uint32_t)h << 16;
    return v.f;
}
__device__ __forceinline__ float fast_tanh(float x) {
    float e = __expf(2.0f * x);               // tanh = 1 - 2/(e^{2x}+1)
    return 1.0f - 2.0f * __builtin_amdgcn_rcpf(e + 1.0f);
}
// Non-temporal float4 store: outputs are never re-read in-kernel; bypass
// L2/L3 so the 96 MB/iter of output traffic stops evicting the read-side
// working set (inputs+state+W ~105 MB) from Infinity Cache.
__device__ __forceinline__ void nt_store4(float* p, float x, float y, float z, float w) {
    f32x4 v = {x, y, z, w};
    __builtin_nontemporal_store(v, (f32x4*)p);
}

// ---------------------------------------------------------------------------
// Kernel 1: ctrl = controls @ W^T via split-bf16 MFMA (3 MFMAs/k-step,
// ~fp32 accuracy).  No LDS, no barriers; A (W rows) and B (controls rows)
// k-contiguous straight from global.  Tile: D[j][b] 16x16.
// ---------------------------------------------------------------------------
__global__ __launch_bounds__(256) void ctrl_gemm(
    const float* __restrict__ controls, const float* __restrict__ W,
    float* __restrict__ ws)
{
    const int tid  = threadIdx.x;
    const int l    = tid & 63;
    const int w    = __builtin_amdgcn_readfirstlane(tid >> 6);
    const int quad = l >> 4;
    const int mlo  = l & 15;
    const int j0   = blockIdx.x * 16;

    const float* wr = W + (size_t)(j0 + mlo) * CTRLN;            // A row (j)
    const float* cr = controls + (size_t)(w * 16 + mlo) * CTRLN; // B row (b)

    f32x4 acc = {0.f, 0.f, 0.f, 0.f};
#pragma unroll 4
    for (int ks = 0; ks < 16; ++ks) {
        const int k0 = ks * 32 + quad * 8;
        const float4 a0 = *(const float4*)(wr + k0);
        const float4 a1 = *(const float4*)(wr + k0 + 4);
        const float4 b0 = *(const float4*)(cr + k0);
        const float4 b1 = *(const float4*)(cr + k0 + 4);
        const float av[8] = {a0.x,a0.y,a0.z,a0.w,a1.x,a1.y,a1.z,a1.w};
        const float bv[8] = {b0.x,b0.y,b0.z,b0.w,b1.x,b1.y,b1.z,b1.w};
        bf8_t ah, al_, bh, bl;
#pragma unroll
        for (int e = 0; e < 8; ++e) {
            const unsigned short hA = f2bf(av[e]);
            ah[e]  = (short)hA;
            al_[e] = (short)f2bf(av[e] - bf2f(hA));
            const unsigned short hB = f2bf(bv[e]);
            bh[e]  = (short)hB;
            bl[e]  = (short)f2bf(bv[e] - bf2f(hB));
        }
        acc = __builtin_amdgcn_mfma_f32_16x16x32_bf16(ah,  bh, acc, 0, 0, 0);
        acc = __builtin_amdgcn_mfma_f32_16x16x32_bf16(ah,  bl, acc, 0, 0, 0);
        acc = __builtin_amdgcn_mfma_f32_16x16x32_bf16(al_, bh, acc, 0, 0, 0);
    }

    // D layout: col = lane&15 -> batch, row = quad*4+reg -> j (4 consecutive)
    const int bidx = w * 16 + mlo;
    float4 r;
    r.x = acc[0]; r.y = acc[1]; r.z = acc[2]; r.w = acc[3];
    *(float4*)(ws + (size_t)bidx * NROWS + j0 + quad * 4) = r;
}

// ---------------------------------------------------------------------------
// Kernel 2: MFMA fused kernel, OUTPUT-TRANSPOSED tiling: D[p][m].
//  - X A-fragments direct from global (no LDS staging).
//  - LDS overlay: Tt reuses IGs bytes after bg-fragments are read.
//    23.3 KB -> 6 blocks/CU (141 KB LDS), VGPR ~44 fits 85-reg cap.
//  - NT stores for both output streams (see nt_store4 comment).
// ---------------------------------------------------------------------------
__global__ __launch_bounds__(256, 6) void vstm_main(
    const float* __restrict__ inputs, const float* __restrict__ state,
    const float* __restrict__ ws, float* __restrict__ out)
{
    __shared__ __align__(16) unsigned char smem[23296];
    unsigned short* const IGs = (unsigned short*)(smem);          // [64][40], phase A
    unsigned short* const Tt  = (unsigned short*)(smem);          // [128][72], overlays IGs
    unsigned short* const OGs = (unsigned short*)(smem + 18432);  // [32][72], persistent
    float*          const fs  = (float*)(smem + 23040);           // [64],     persistent

    const int tid  = threadIdx.x;
    const int b    = blockIdx.y;
    const int tile = blockIdx.x * TILE;
    const int w    = __builtin_amdgcn_readfirstlane(tid >> 6);
    const int l    = tid & 63;
    const int quad = l >> 4;
    const int mlo  = l & 15;

    // ---- gate loads (gate barrier 1) ----
    const float* g = ws + (size_t)b * NROWS;
    const float fsv = g[tid & 63];
    float4 giv[2], gov[2];
#pragma unroll
    for (int i = 0; i < 2; ++i) {
        const int e = (i * 256 + tid) * 4;                   // 0..2044
        giv[i] = *(const float4*)(g + 64 + e);               // ig[m*32+c]
        gov[i] = *(const float4*)(g + 2112 + e);             // og[o*64+m]
    }

    // ---- X fragment loads (direct from global, coalesced b32) ----
    const float* xb = inputs + (size_t)b * IN_CH * HW + tile + w * 32;
    float xf[2][8];
#pragma unroll
    for (int pc = 0; pc < 2; ++pc)
#pragma unroll
        for (int j = 0; j < 8; ++j)
            xf[pc][j] = xb[(size_t)(quad * 8 + j) * HW + pc * 16 + mlo];

    // ---- state loads (consumed in epilogue) ----
    const float* stb = state + (size_t)b * NMAPS * HW + tile;
    float4 stv[4][2];
#pragma unroll
    for (int mc = 0; mc < 4; ++mc)
#pragma unroll
        for (int pc = 0; pc < 2; ++pc)
            stv[mc][pc] = *(const float4*)(stb + (size_t)(mc * 16 + mlo) * HW
                                           + w * 32 + pc * 16 + quad * 4);

    // ---- stage gates to LDS ----
    if (tid < 64) fs[tid] = fsv;
#pragma unroll
    for (int i = 0; i < 2; ++i) {
        const int e = (i * 256 + tid) * 4;
        bf4_t vi = { (short)f2bf(giv[i].x), (short)f2bf(giv[i].y),
                     (short)f2bf(giv[i].z), (short)f2bf(giv[i].w) };
        *(bf4_t*)&IGs[(e >> 5) * 40 + (e & 31)] = vi;
        bf4_t vo = { (short)f2bf(gov[i].x), (short)f2bf(gov[i].y),
                     (short)f2bf(gov[i].z), (short)f2bf(gov[i].w) };
        *(bf4_t*)&OGs[(e >> 6) * 72 + (e & 63)] = vo;
    }
    __syncthreads();                        // barrier 1: gates staged

    // ---- B-fragments (IG) from LDS ----
    bf8_t bg[4];
#pragma unroll
    for (int mc = 0; mc < 4; ++mc)
        bg[mc] = *(const bf8_t*)&IGs[(mc * 16 + mlo) * 40 + quad * 8];

    // ---- A-fragments from xf (register-only conversion) ----
    bf8_t af[2];
#pragma unroll
    for (int pc = 0; pc < 2; ++pc)
#pragma unroll
        for (int j = 0; j < 8; ++j)
            af[pc][j] = (short)f2bf(xf[pc][j]);

    __syncthreads();                        // barrier 2: IGs consumed -> Tt may overwrite

    // ---- Phase A: D[p][m], wave w owns p in [32w, 32w+32) ----
    f32x4 acc[2][4];
#pragma unroll
    for (int pc = 0; pc < 2; ++pc)
#pragma unroll
        for (int mc = 0; mc < 4; ++mc) {
            acc[pc][mc] = (f32x4){0.f, 0.f, 0.f, 0.f};
            acc[pc][mc] = __builtin_amdgcn_mfma_f32_16x16x32_bf16(
                af[pc], bg[mc], acc[pc][mc], 0, 0, 0);
        }

    // ---- epilogue: ns = acc + state*f, NT float4 write, tanh -> Tt bf16 ----
    float* nsb = out + OUT0_SZ + (size_t)b * NMAPS * HW + tile;
#pragma unroll
    for (int mc = 0; mc < 4; ++mc) {
        const int m = mc * 16 + mlo;
        const float fgt = fs[m];
#pragma unroll
        for (int pc = 0; pc < 2; ++pc) {
            const int p0 = w * 32 + pc * 16 + quad * 4;
            const float4 st = stv[mc][pc];
            float nsx = acc[pc][mc][0] + st.x * fgt;
            float nsy = acc[pc][mc][1] + st.y * fgt;
            float nsz = acc[pc][mc][2] + st.z * fgt;
            float nsw = acc[pc][mc][3] + st.w * fgt;
            nt_store4(nsb + (size_t)m * HW + p0, nsx, nsy, nsz, nsw);
            Tt[(p0 + 0) * 72 + m] = f2bf(fast_tanh(nsx));
            Tt[(p0 + 1) * 72 + m] = f2bf(fast_tanh(nsy));
            Tt[(p0 + 2) * 72 + m] = f2bf(fast_tanh(nsz));
            Tt[(p0 + 3) * 72 + m] = f2bf(fast_tanh(nsw));
        }
    }
    // no barrier: wave w reads only Tt rows it wrote

    // ---- Phase B: D[p][o] = T^T[p][m] x OG^T[m][o], K=64 -> 2 steps ----
    bf8_t ag[2][2], at[2][2];
#pragma unroll
    for (int oc = 0; oc < 2; ++oc)
#pragma unroll
        for (int ks = 0; ks < 2; ++ks)
            ag[oc][ks] = *(const bf8_t*)&OGs[(oc * 16 + mlo) * 72 + ks * 32 + quad * 8];
#pragma unroll
    for (int pc = 0; pc < 2; ++pc)
#pragma unroll
        for (int ks = 0; ks < 2; ++ks)
            at[pc][ks] = *(const bf8_t*)&Tt[(w * 32 + pc * 16 + mlo) * 72 + ks * 32 + quad * 8];

    f32x4 acc2[2][2];
#pragma unroll
    for (int pc = 0; pc < 2; ++pc)
#pragma unroll
        for (int oc = 0; oc < 2; ++oc) {
            acc2[pc][oc] = (f32x4){0.f, 0.f, 0.f, 0.f};
#pragma unroll
            for (int ks = 0; ks < 2; ++ks)
                acc2[pc][oc] = __builtin_amdgcn_mfma_f32_16x16x32_bf16(
                    at[pc][ks], ag[oc][ks], acc2[pc][oc], 0, 0, 0);
        }

    float* ob = out + (size_t)b * OUT_CH * HW + tile;
#pragma unroll
    for (int pc = 0; pc < 2; ++pc)
#pragma unroll
        for (int oc = 0; oc < 2; ++oc) {
            const int p0 = w * 32 + pc * 16 + quad * 4;
            const int o  = oc * 16 + mlo;
            nt_store4(ob + (size_t)o * HW + p0,
                      acc2[pc][oc][0], acc2[pc][oc][1],
                      acc2[pc][oc][2], acc2[pc][oc][3]);
        }
}

extern "C" void kernel_launch(void* const* d_in, const int* in_sizes, int n_in,
                              void* d_out, int out_size, void* d_ws, size_t ws_size,
                              hipStream_t stream) {
    const float* inputs   = (const float*)d_in[0];
    const float* state    = (const float*)d_in[1];
    const float* controls = (const float*)d_in[2];
    const float* W        = (const float*)d_in[3];
    float*       out      = (float*)d_out;
    float*       ws       = (float*)d_ws;

    ctrl_gemm<<<dim3(NROWS / 16), 256, 0, stream>>>(controls, W, ws);

    dim3 g2(HW / TILE, B_SZ);
    vstm_main<<<g2, 256, 0, stream>>>(inputs, state, ws, out);
}

// Round 3
// 209.374 us; speedup vs baseline: 1.0534x; 1.0534x over previous
//
#include <hip/hip_runtime.h>
#include <cstdint>
#include <cstddef>

// Problem constants
#define B_SZ   64
#define IN_CH  32
#define OUT_CH 32
#define NMAPS  64
#define HW     4096          // 64*64
#define CTRLN  512
#define NROWS  4160          // NF(64) + NI(2048) + NO(2048)
#define OUT0_SZ (B_SZ*OUT_CH*HW)
#define TILE   128

typedef short bf8_t  __attribute__((ext_vector_type(8)));   // 8 bf16 = 4 VGPR
typedef short bf4_t  __attribute__((ext_vector_type(4)));   // 4 bf16 = 2 VGPR
typedef float f32x4  __attribute__((ext_vector_type(4)));

__device__ __forceinline__ unsigned short f2bf(float f) {
    union { float f; uint32_t u; } v; v.f = f;
    return (unsigned short)((v.u + 0x7FFFu + ((v.u >> 16) & 1u)) >> 16);  // RNE
}
__device__ __forceinline__ float bf2f(unsigned short h) {
    union { uint32_t u; float f; } v; v.u = (uint32_t)h << 16;
    return v.f;
}
__device__ __forceinline__ float fast_tanh(float x) {
    float e = __expf(2.0f * x);               // tanh = 1 - 2/(e^{2x}+1)
    return 1.0f - 2.0f * __builtin_amdgcn_rcpf(e + 1.0f);
}

// ---------------------------------------------------------------------------
// Kernel 1: ctrl = controls @ W^T via split-bf16 MFMA (3 MFMAs/k-step,
// ~fp32 accuracy).  No LDS, no barriers; A (W rows) and B (controls rows)
// k-contiguous straight from global.  Tile: D[j][b] 16x16.
// ---------------------------------------------------------------------------
__global__ __launch_bounds__(256) void ctrl_gemm(
    const float* __restrict__ controls, const float* __restrict__ W,
    float* __restrict__ ws)
{
    const int tid  = threadIdx.x;
    const int l    = tid & 63;
    const int w    = __builtin_amdgcn_readfirstlane(tid >> 6);
    const int quad = l >> 4;
    const int mlo  = l & 15;
    const int j0   = blockIdx.x * 16;

    const float* wr = W + (size_t)(j0 + mlo) * CTRLN;            // A row (j)
    const float* cr = controls + (size_t)(w * 16 + mlo) * CTRLN; // B row (b)

    f32x4 acc = {0.f, 0.f, 0.f, 0.f};
#pragma unroll 4
    for (int ks = 0; ks < 16; ++ks) {
        const int k0 = ks * 32 + quad * 8;
        const float4 a0 = *(const float4*)(wr + k0);
        const float4 a1 = *(const float4*)(wr + k0 + 4);
        const float4 b0 = *(const float4*)(cr + k0);
        const float4 b1 = *(const float4*)(cr + k0 + 4);
        const float av[8] = {a0.x,a0.y,a0.z,a0.w,a1.x,a1.y,a1.z,a1.w};
        const float bv[8] = {b0.x,b0.y,b0.z,b0.w,b1.x,b1.y,b1.z,b1.w};
        bf8_t ah, al_, bh, bl;
#pragma unroll
        for (int e = 0; e < 8; ++e) {
            const unsigned short hA = f2bf(av[e]);
            ah[e]  = (short)hA;
            al_[e] = (short)f2bf(av[e] - bf2f(hA));
            const unsigned short hB = f2bf(bv[e]);
            bh[e]  = (short)hB;
            bl[e]  = (short)f2bf(bv[e] - bf2f(hB));
        }
        acc = __builtin_amdgcn_mfma_f32_16x16x32_bf16(ah,  bh, acc, 0, 0, 0);
        acc = __builtin_amdgcn_mfma_f32_16x16x32_bf16(ah,  bl, acc, 0, 0, 0);
        acc = __builtin_amdgcn_mfma_f32_16x16x32_bf16(al_, bh, acc, 0, 0, 0);
    }

    // D layout: col = lane&15 -> batch, row = quad*4+reg -> j (4 consecutive)
    const int bidx = w * 16 + mlo;
    float4 r;
    r.x = acc[0]; r.y = acc[1]; r.z = acc[2]; r.w = acc[3];
    *(float4*)(ws + (size_t)bidx * NROWS + j0 + quad * 4) = r;
}

// ---------------------------------------------------------------------------
// Kernel 2: MFMA fused kernel, OUTPUT-TRANSPOSED tiling: D[p][m].
// R3 change: FORCED memory-level parallelism.  R1/R2 machine code had
// VGPR=40-44 -> the compiler sank all prefetches to their use sites
// (~4-8 outstanding loads/wave, delivered BW stuck at ~3.1 TB/s).  Here
// all 28 load instructions (gates 4, xf 16, stv 8) are issued at kernel
// top and pinned there with sched_barrier(0), which no instruction may
// cross.  Issue order gates->xf->stv lets the LDS gate-staging wait with
// a partial vmcnt while xf/stv remain in flight.  ~110 VGPR ->
// __launch_bounds__(256,4): 4 blocks/CU (R2 proved 6 blocks buys nothing,
// so occupancy is traded for 3.5x MLP).  Stores are cached float4 again
// (R2: NT stores broke L2 write-combining of the 16x16B lane pattern,
// 1.44x write amplification).
// ---------------------------------------------------------------------------
__global__ __launch_bounds__(256, 4) void vstm_main(
    const float* __restrict__ inputs, const float* __restrict__ state,
    const float* __restrict__ ws, float* __restrict__ out)
{
    __shared__ __align__(16) unsigned char smem[23296];
    unsigned short* const IGs = (unsigned short*)(smem);          // [64][40], phase A
    unsigned short* const Tt  = (unsigned short*)(smem);          // [128][72], overlays IGs
    unsigned short* const OGs = (unsigned short*)(smem + 18432);  // [32][72], persistent
    float*          const fs  = (float*)(smem + 23040);           // [64],     persistent

    const int tid  = threadIdx.x;
    const int b    = blockIdx.y;
    const int tile = blockIdx.x * TILE;
    const int w    = __builtin_amdgcn_readfirstlane(tid >> 6);
    const int l    = tid & 63;
    const int quad = l >> 4;
    const int mlo  = l & 15;

    // ================= load-issue block (pinned by sched_barrier) =========
    // ---- gate loads (gate barrier 1; issued first so their vmcnt drains
    //      first and LDS staging can start while xf/stv are in flight) ----
    const float* g = ws + (size_t)b * NROWS;
    const float fsv = g[tid & 63];
    float4 giv[2], gov[2];
#pragma unroll
    for (int i = 0; i < 2; ++i) {
        const int e = (i * 256 + tid) * 4;                   // 0..2044
        giv[i] = *(const float4*)(g + 64 + e);               // ig[m*32+c]
        gov[i] = *(const float4*)(g + 2112 + e);             // og[o*64+m]
    }

    // ---- X fragment loads (direct from global, coalesced b32) ----
    const float* xb = inputs + (size_t)b * IN_CH * HW + tile + w * 32;
    float xf[2][8];
#pragma unroll
    for (int pc = 0; pc < 2; ++pc)
#pragma unroll
        for (int j = 0; j < 8; ++j)
            xf[pc][j] = xb[(size_t)(quad * 8 + j) * HW + pc * 16 + mlo];

    // ---- state loads (consumed in epilogue) ----
    const float* stb = state + (size_t)b * NMAPS * HW + tile;
    float4 stv[4][2];
#pragma unroll
    for (int mc = 0; mc < 4; ++mc)
#pragma unroll
        for (int pc = 0; pc < 2; ++pc)
            stv[mc][pc] = *(const float4*)(stb + (size_t)(mc * 16 + mlo) * HW
                                           + w * 32 + pc * 16 + quad * 4);

    // Nothing may move across this point: all 28 loads stay issued above.
    __builtin_amdgcn_sched_barrier(0);
    // ======================================================================

    // ---- stage gates to LDS (waits only the gate loads' vmcnt) ----
    if (tid < 64) fs[tid] = fsv;
#pragma unroll
    for (int i = 0; i < 2; ++i) {
        const int e = (i * 256 + tid) * 4;
        bf4_t vi = { (short)f2bf(giv[i].x), (short)f2bf(giv[i].y),
                     (short)f2bf(giv[i].z), (short)f2bf(giv[i].w) };
        *(bf4_t*)&IGs[(e >> 5) * 40 + (e & 31)] = vi;
        bf4_t vo = { (short)f2bf(gov[i].x), (short)f2bf(gov[i].y),
                     (short)f2bf(gov[i].z), (short)f2bf(gov[i].w) };
        *(bf4_t*)&OGs[(e >> 6) * 72 + (e & 63)] = vo;
    }
    __syncthreads();                        // barrier 1: gates staged

    // ---- B-fragments (IG) from LDS ----
    bf8_t bg[4];
#pragma unroll
    for (int mc = 0; mc < 4; ++mc)
        bg[mc] = *(const bf8_t*)&IGs[(mc * 16 + mlo) * 40 + quad * 8];

    // ---- A-fragments from xf (register-only conversion) ----
    bf8_t af[2];
#pragma unroll
    for (int pc = 0; pc < 2; ++pc)
#pragma unroll
        for (int j = 0; j < 8; ++j)
            af[pc][j] = (short)f2bf(xf[pc][j]);

    __syncthreads();                        // barrier 2: IGs consumed -> Tt may overwrite

    // ---- Phase A: D[p][m], wave w owns p in [32w, 32w+32) ----
    f32x4 acc[2][4];
#pragma unroll
    for (int pc = 0; pc < 2; ++pc)
#pragma unroll
        for (int mc = 0; mc < 4; ++mc) {
            acc[pc][mc] = (f32x4){0.f, 0.f, 0.f, 0.f};
            acc[pc][mc] = __builtin_amdgcn_mfma_f32_16x16x32_bf16(
                af[pc], bg[mc], acc[pc][mc], 0, 0, 0);
        }

    // ---- epilogue: ns = acc + state*f (state already in regs), float4 I/O,
    //      tanh -> Tt[p][m] bf16 (wave-private rows) ----
    float* nsb = out + OUT0_SZ + (size_t)b * NMAPS * HW + tile;
#pragma unroll
    for (int mc = 0; mc < 4; ++mc) {
        const int m = mc * 16 + mlo;
        const float fgt = fs[m];
#pragma unroll
        for (int pc = 0; pc < 2; ++pc) {
            const int p0 = w * 32 + pc * 16 + quad * 4;
            const float4 st = stv[mc][pc];
            float4 ns;
            ns.x = acc[pc][mc][0] + st.x * fgt;
            ns.y = acc[pc][mc][1] + st.y * fgt;
            ns.z = acc[pc][mc][2] + st.z * fgt;
            ns.w = acc[pc][mc][3] + st.w * fgt;
            *(float4*)(nsb + (size_t)m * HW + p0) = ns;
            Tt[(p0 + 0) * 72 + m] = f2bf(fast_tanh(ns.x));
            Tt[(p0 + 1) * 72 + m] = f2bf(fast_tanh(ns.y));
            Tt[(p0 + 2) * 72 + m] = f2bf(fast_tanh(ns.z));
            Tt[(p0 + 3) * 72 + m] = f2bf(fast_tanh(ns.w));
        }
    }
    // no barrier: wave w reads only Tt rows it wrote

    // ---- Phase B: D[p][o] = T^T[p][m] x OG^T[m][o], K=64 -> 2 steps ----
    bf8_t ag[2][2], at[2][2];
#pragma unroll
    for (int oc = 0; oc < 2; ++oc)
#pragma unroll
        for (int ks = 0; ks < 2; ++ks)
            ag[oc][ks] = *(const bf8_t*)&OGs[(oc * 16 + mlo) * 72 + ks * 32 + quad * 8];
#pragma unroll
    for (int pc = 0; pc < 2; ++pc)
#pragma unroll
        for (int ks = 0; ks < 2; ++ks)
            at[pc][ks] = *(const bf8_t*)&Tt[(w * 32 + pc * 16 + mlo) * 72 + ks * 32 + quad * 8];

    f32x4 acc2[2][2];
#pragma unroll
    for (int pc = 0; pc < 2; ++pc)
#pragma unroll
        for (int oc = 0; oc < 2; ++oc) {
            acc2[pc][oc] = (f32x4){0.f, 0.f, 0.f, 0.f};
#pragma unroll
            for (int ks = 0; ks < 2; ++ks)
                acc2[pc][oc] = __builtin_amdgcn_mfma_f32_16x16x32_bf16(
                    at[pc][ks], ag[oc][ks], acc2[pc][oc], 0, 0, 0);
        }

    float* ob = out + (size_t)b * OUT_CH * HW + tile;
#pragma unroll
    for (int pc = 0; pc < 2; ++pc)
#pragma unroll
        for (int oc = 0; oc < 2; ++oc) {
            const int p0 = w * 32 + pc * 16 + quad * 4;
            const int o  = oc * 16 + mlo;
            float4 r;
            r.x = acc2[pc][oc][0];
            r.y = acc2[pc][oc][1];
            r.z = acc2[pc][oc][2];
            r.w = acc2[pc][oc][3];
            *(float4*)(ob + (size_t)o * HW + p0) = r;
        }
}

extern "C" void kernel_launch(void* const* d_in, const int* in_sizes, int n_in,
                              void* d_out, int out_size, void* d_ws, size_t ws_size,
                              hipStream_t stream) {
    const float* inputs   = (const float*)d_in[0];
    const float* state    = (const float*)d_in[1];
    const float* controls = (const float*)d_in[2];
    const float* W        = (const float*)d_in[3];
    float*       out      = (float*)d_out;
    float*       ws       = (float*)d_ws;

    ctrl_gemm<<<dim3(NROWS / 16), 256, 0, stream>>>(controls, W, ws);

    dim3 g2(HW / TILE, B_SZ);
    vstm_main<<<g2, 256, 0, stream>>>(inputs, state, ws, out);
}

// Round 4
// 209.000 us; speedup vs baseline: 1.0553x; 1.0018x over previous
//
#include <hip/hip_runtime.h>
#include <cstdint>
#include <cstddef>

// Problem constants
#define B_SZ   64
#define IN_CH  32
#define OUT_CH 32
#define NMAPS  64
#define HW     4096          // 64*64
#define CTRLN  512
#define NROWS  4160          // NF(64) + NI(2048) + NO(2048)
#define OUT0_SZ (B_SZ*OUT_CH*HW)
#define TILE   128

typedef short bf8_t  __attribute__((ext_vector_type(8)));   // 8 bf16 = 4 VGPR
typedef short bf4_t  __attribute__((ext_vector_type(4)));   // 4 bf16 = 2 VGPR
typedef float f32x4  __attribute__((ext_vector_type(4)));

__device__ __forceinline__ unsigned short f2bf(float f) {
    union { float f; uint32_t u; } v; v.f = f;
    return (unsigned short)((v.u + 0x7FFFu + ((v.u >> 16) & 1u)) >> 16);  // RNE
}
__device__ __forceinline__ float bf2f(unsigned short h) {
    union { uint32_t u; float f; } v; v.u = (uint32_t)h << 16;
    return v.f;
}
__device__ __forceinline__ float fast_tanh(float x) {
    float e = __expf(2.0f * x);               // tanh = 1 - 2/(e^{2x}+1)
    return 1.0f - 2.0f * __builtin_amdgcn_rcpf(e + 1.0f);
}
// Materialization pins: an inline-asm REGISTER USE of a loaded value is the
// one thing machine-sinking cannot move a load past (R3 lesson: sched_barrier
// alone is not a use and got ignored; VGPR stayed 44).  Placing these right
// after the load-issue block forces all loads to issue back-to-back (one
// collective drain instead of 3-4 serial latency exposures per wave).
__device__ __forceinline__ void keep1(float& a) {
    asm volatile("" : "+v"(a));
}
__device__ __forceinline__ void keep4(float4& v) {
    asm volatile("" : "+v"(v.x), "+v"(v.y), "+v"(v.z), "+v"(v.w));
}

// ---------------------------------------------------------------------------
// Kernel 1: ctrl = controls @ W^T via split-bf16 MFMA (3 MFMAs/k-step,
// ~fp32 accuracy).  No LDS, no barriers; A (W rows) and B (controls rows)
// k-contiguous straight from global.  Tile: D[j][b] 16x16.
// ---------------------------------------------------------------------------
__global__ __launch_bounds__(256) void ctrl_gemm(
    const float* __restrict__ controls, const float* __restrict__ W,
    float* __restrict__ ws)
{
    const int tid  = threadIdx.x;
    const int l    = tid & 63;
    const int w    = __builtin_amdgcn_readfirstlane(tid >> 6);
    const int quad = l >> 4;
    const int mlo  = l & 15;
    const int j0   = blockIdx.x * 16;

    const float* wr = W + (size_t)(j0 + mlo) * CTRLN;            // A row (j)
    const float* cr = controls + (size_t)(w * 16 + mlo) * CTRLN; // B row (b)

    f32x4 acc = {0.f, 0.f, 0.f, 0.f};
#pragma unroll 4
    for (int ks = 0; ks < 16; ++ks) {
        const int k0 = ks * 32 + quad * 8;
        const float4 a0 = *(const float4*)(wr + k0);
        const float4 a1 = *(const float4*)(wr + k0 + 4);
        const float4 b0 = *(const float4*)(cr + k0);
        const float4 b1 = *(const float4*)(cr + k0 + 4);
        const float av[8] = {a0.x,a0.y,a0.z,a0.w,a1.x,a1.y,a1.z,a1.w};
        const float bv[8] = {b0.x,b0.y,b0.z,b0.w,b1.x,b1.y,b1.z,b1.w};
        bf8_t ah, al_, bh, bl;
#pragma unroll
        for (int e = 0; e < 8; ++e) {
            const unsigned short hA = f2bf(av[e]);
            ah[e]  = (short)hA;
            al_[e] = (short)f2bf(av[e] - bf2f(hA));
            const unsigned short hB = f2bf(bv[e]);
            bh[e]  = (short)hB;
            bl[e]  = (short)f2bf(bv[e] - bf2f(hB));
        }
        acc = __builtin_amdgcn_mfma_f32_16x16x32_bf16(ah,  bh, acc, 0, 0, 0);
        acc = __builtin_amdgcn_mfma_f32_16x16x32_bf16(ah,  bl, acc, 0, 0, 0);
        acc = __builtin_amdgcn_mfma_f32_16x16x32_bf16(al_, bh, acc, 0, 0, 0);
    }

    // D layout: col = lane&15 -> batch, row = quad*4+reg -> j (4 consecutive)
    const int bidx = w * 16 + mlo;
    float4 r;
    r.x = acc[0]; r.y = acc[1]; r.z = acc[2]; r.w = acc[3];
    *(float4*)(ws + (size_t)bidx * NROWS + j0 + quad * 4) = r;
}

// ---------------------------------------------------------------------------
// Kernel 2: MFMA fused kernel, OUTPUT-TRANSPOSED tiling: D[p][m].
// R4: forced memory-level parallelism via keep1/keep4 materialization pins.
// All 28 load instructions (gates 4+1, xf 16, stv 8) issue back-to-back at
// kernel top, then one collective drain; downstream is pure LDS/compute.
// Peak live regs ~100-110 -> __launch_bounds__(256,4) (128-reg cap, no
// spill).  Cached float4 stores (R2: NT stores caused 1.44x write
// amplification by defeating L2 write-combining of the 16x16B lane pattern).
// ---------------------------------------------------------------------------
__global__ __launch_bounds__(256, 4) void vstm_main(
    const float* __restrict__ inputs, const float* __restrict__ state,
    const float* __restrict__ ws, float* __restrict__ out)
{
    __shared__ __align__(16) unsigned char smem[23296];
    unsigned short* const IGs = (unsigned short*)(smem);          // [64][40], phase A
    unsigned short* const Tt  = (unsigned short*)(smem);          // [128][72], overlays IGs
    unsigned short* const OGs = (unsigned short*)(smem + 18432);  // [32][72], persistent
    float*          const fs  = (float*)(smem + 23040);           // [64],     persistent

    const int tid  = threadIdx.x;
    const int b    = blockIdx.y;
    const int tile = blockIdx.x * TILE;
    const int w    = __builtin_amdgcn_readfirstlane(tid >> 6);
    const int l    = tid & 63;
    const int quad = l >> 4;
    const int mlo  = l & 15;

    // ================= load-issue block =====================================
    const float* g = ws + (size_t)b * NROWS;
    float fsv = g[tid & 63];
    float4 giv[2], gov[2];
#pragma unroll
    for (int i = 0; i < 2; ++i) {
        const int e = (i * 256 + tid) * 4;                   // 0..2044
        giv[i] = *(const float4*)(g + 64 + e);               // ig[m*32+c]
        gov[i] = *(const float4*)(g + 2112 + e);             // og[o*64+m]
    }

    const float* xb = inputs + (size_t)b * IN_CH * HW + tile + w * 32;
    float xf[2][8];
#pragma unroll
    for (int pc = 0; pc < 2; ++pc)
#pragma unroll
        for (int j = 0; j < 8; ++j)
            xf[pc][j] = xb[(size_t)(quad * 8 + j) * HW + pc * 16 + mlo];

    const float* stb = state + (size_t)b * NMAPS * HW + tile;
    float4 stv[4][2];
#pragma unroll
    for (int mc = 0; mc < 4; ++mc)
#pragma unroll
        for (int pc = 0; pc < 2; ++pc)
            stv[mc][pc] = *(const float4*)(stb + (size_t)(mc * 16 + mlo) * HW
                                           + w * 32 + pc * 16 + quad * 4);

    // ---- materialization pins: loads may not sink below this point ----
    keep1(fsv);
    keep4(giv[0]); keep4(giv[1]); keep4(gov[0]); keep4(gov[1]);
#pragma unroll
    for (int pc = 0; pc < 2; ++pc)
#pragma unroll
        for (int j = 0; j < 8; ++j)
            keep1(xf[pc][j]);
#pragma unroll
    for (int mc = 0; mc < 4; ++mc)
#pragma unroll
        for (int pc = 0; pc < 2; ++pc)
            keep4(stv[mc][pc]);
    // ========================================================================

    // ---- stage gates to LDS ----
    if (tid < 64) fs[tid] = fsv;
#pragma unroll
    for (int i = 0; i < 2; ++i) {
        const int e = (i * 256 + tid) * 4;
        bf4_t vi = { (short)f2bf(giv[i].x), (short)f2bf(giv[i].y),
                     (short)f2bf(giv[i].z), (short)f2bf(giv[i].w) };
        *(bf4_t*)&IGs[(e >> 5) * 40 + (e & 31)] = vi;
        bf4_t vo = { (short)f2bf(gov[i].x), (short)f2bf(gov[i].y),
                     (short)f2bf(gov[i].z), (short)f2bf(gov[i].w) };
        *(bf4_t*)&OGs[(e >> 6) * 72 + (e & 63)] = vo;
    }
    __syncthreads();                        // barrier 1: gates staged

    // ---- B-fragments (IG) from LDS ----
    bf8_t bg[4];
#pragma unroll
    for (int mc = 0; mc < 4; ++mc)
        bg[mc] = *(const bf8_t*)&IGs[(mc * 16 + mlo) * 40 + quad * 8];

    // ---- A-fragments from xf (register-only conversion) ----
    bf8_t af[2];
#pragma unroll
    for (int pc = 0; pc < 2; ++pc)
#pragma unroll
        for (int j = 0; j < 8; ++j)
            af[pc][j] = (short)f2bf(xf[pc][j]);

    __syncthreads();                        // barrier 2: IGs consumed -> Tt may overwrite

    // ---- Phase A: D[p][m], wave w owns p in [32w, 32w+32) ----
    f32x4 acc[2][4];
#pragma unroll
    for (int pc = 0; pc < 2; ++pc)
#pragma unroll
        for (int mc = 0; mc < 4; ++mc) {
            acc[pc][mc] = (f32x4){0.f, 0.f, 0.f, 0.f};
            acc[pc][mc] = __builtin_amdgcn_mfma_f32_16x16x32_bf16(
                af[pc], bg[mc], acc[pc][mc], 0, 0, 0);
        }

    // ---- epilogue: ns = acc + state*f (state already in regs), float4 I/O,
    //      tanh -> Tt[p][m] bf16 (wave-private rows) ----
    float* nsb = out + OUT0_SZ + (size_t)b * NMAPS * HW + tile;
#pragma unroll
    for (int mc = 0; mc < 4; ++mc) {
        const int m = mc * 16 + mlo;
        const float fgt = fs[m];
#pragma unroll
        for (int pc = 0; pc < 2; ++pc) {
            const int p0 = w * 32 + pc * 16 + quad * 4;
            const float4 st = stv[mc][pc];
            float4 ns;
            ns.x = acc[pc][mc][0] + st.x * fgt;
            ns.y = acc[pc][mc][1] + st.y * fgt;
            ns.z = acc[pc][mc][2] + st.z * fgt;
            ns.w = acc[pc][mc][3] + st.w * fgt;
            *(float4*)(nsb + (size_t)m * HW + p0) = ns;
            Tt[(p0 + 0) * 72 + m] = f2bf(fast_tanh(ns.x));
            Tt[(p0 + 1) * 72 + m] = f2bf(fast_tanh(ns.y));
            Tt[(p0 + 2) * 72 + m] = f2bf(fast_tanh(ns.z));
            Tt[(p0 + 3) * 72 + m] = f2bf(fast_tanh(ns.w));
        }
    }
    // no barrier: wave w reads only Tt rows it wrote

    // ---- Phase B: D[p][o] = T^T[p][m] x OG^T[m][o], K=64 -> 2 steps ----
    bf8_t ag[2][2], at[2][2];
#pragma unroll
    for (int oc = 0; oc < 2; ++oc)
#pragma unroll
        for (int ks = 0; ks < 2; ++ks)
            ag[oc][ks] = *(const bf8_t*)&OGs[(oc * 16 + mlo) * 72 + ks * 32 + quad * 8];
#pragma unroll
    for (int pc = 0; pc < 2; ++pc)
#pragma unroll
        for (int ks = 0; ks < 2; ++ks)
            at[pc][ks] = *(const bf8_t*)&Tt[(w * 32 + pc * 16 + mlo) * 72 + ks * 32 + quad * 8];

    f32x4 acc2[2][2];
#pragma unroll
    for (int pc = 0; pc < 2; ++pc)
#pragma unroll
        for (int oc = 0; oc < 2; ++oc) {
            acc2[pc][oc] = (f32x4){0.f, 0.f, 0.f, 0.f};
#pragma unroll
            for (int ks = 0; ks < 2; ++ks)
                acc2[pc][oc] = __builtin_amdgcn_mfma_f32_16x16x32_bf16(
                    at[pc][ks], ag[oc][ks], acc2[pc][oc], 0, 0, 0);
        }

    float* ob = out + (size_t)b * OUT_CH * HW + tile;
#pragma unroll
    for (int pc = 0; pc < 2; ++pc)
#pragma unroll
        for (int oc = 0; oc < 2; ++oc) {
            const int p0 = w * 32 + pc * 16 + quad * 4;
            const int o  = oc * 16 + mlo;
            float4 r;
            r.x = acc2[pc][oc][0];
            r.y = acc2[pc][oc][1];
            r.z = acc2[pc][oc][2];
            r.w = acc2[pc][oc][3];
            *(float4*)(ob + (size_t)o * HW + p0) = r;
        }
}

extern "C" void kernel_launch(void* const* d_in, const int* in_sizes, int n_in,
                              void* d_out, int out_size, void* d_ws, size_t ws_size,
                              hipStream_t stream) {
    const float* inputs   = (const float*)d_in[0];
    const float* state    = (const float*)d_in[1];
    const float* controls = (const float*)d_in[2];
    const float* W        = (const float*)d_in[3];
    float*       out      = (float*)d_out;
    float*       ws       = (float*)d_ws;

    ctrl_gemm<<<dim3(NROWS / 16), 256, 0, stream>>>(controls, W, ws);

    dim3 g2(HW / TILE, B_SZ);
    vstm_main<<<g2, 256, 0, stream>>>(inputs, state, ws, out);
}

// Round 5
// 208.457 us; speedup vs baseline: 1.0581x; 1.0026x over previous
//
#include <hip/hip_runtime.h>
#include <cstdint>
#include <cstddef>

// Problem constants
#define B_SZ   64
#define IN_CH  32
#define OUT_CH 32
#define NMAPS  64
#define HW     4096          // 64*64
#define CTRLN  512
#define NROWS  4160          // NF(64) + NI(2048) + NO(2048)
#define OUT0_SZ (B_SZ*OUT_CH*HW)
#define TILE   128

typedef short bf8_t  __attribute__((ext_vector_type(8)));   // 8 bf16 = 4 VGPR
typedef short bf4_t  __attribute__((ext_vector_type(4)));   // 4 bf16 = 2 VGPR
typedef float f32x4  __attribute__((ext_vector_type(4)));

__device__ __forceinline__ unsigned short f2bf(float f) {
    union { float f; uint32_t u; } v; v.f = f;
    return (unsigned short)((v.u + 0x7FFFu + ((v.u >> 16) & 1u)) >> 16);  // RNE
}
__device__ __forceinline__ float bf2f(unsigned short h) {
    union { uint32_t u; float f; } v; v.u = (uint32_t)h << 16;
    return v.f;
}
__device__ __forceinline__ float fast_tanh(float x) {
    float e = __expf(2.0f * x);               // tanh = 1 - 2/(e^{2x}+1)
    return 1.0f - 2.0f * __builtin_amdgcn_rcpf(e + 1.0f);
}

// ---------------------------------------------------------------------------
// Kernel 1: ctrl = controls @ W^T via split-bf16 MFMA (3 MFMAs/k-step,
// ~fp32 accuracy).  No LDS, no barriers; A (W rows) and B (controls rows)
// k-contiguous straight from global.  Tile: D[j][b] 16x16.
// ---------------------------------------------------------------------------
__global__ __launch_bounds__(256) void ctrl_gemm(
    const float* __restrict__ controls, const float* __restrict__ W,
    float* __restrict__ ws)
{
    const int tid  = threadIdx.x;
    const int l    = tid & 63;
    const int w    = __builtin_amdgcn_readfirstlane(tid >> 6);
    const int quad = l >> 4;
    const int mlo  = l & 15;
    const int j0   = blockIdx.x * 16;

    const float* wr = W + (size_t)(j0 + mlo) * CTRLN;            // A row (j)
    const float* cr = controls + (size_t)(w * 16 + mlo) * CTRLN; // B row (b)

    f32x4 acc = {0.f, 0.f, 0.f, 0.f};
#pragma unroll 4
    for (int ks = 0; ks < 16; ++ks) {
        const int k0 = ks * 32 + quad * 8;
        const float4 a0 = *(const float4*)(wr + k0);
        const float4 a1 = *(const float4*)(wr + k0 + 4);
        const float4 b0 = *(const float4*)(cr + k0);
        const float4 b1 = *(const float4*)(cr + k0 + 4);
        const float av[8] = {a0.x,a0.y,a0.z,a0.w,a1.x,a1.y,a1.z,a1.w};
        const float bv[8] = {b0.x,b0.y,b0.z,b0.w,b1.x,b1.y,b1.z,b1.w};
        bf8_t ah, al_, bh, bl;
#pragma unroll
        for (int e = 0; e < 8; ++e) {
            const unsigned short hA = f2bf(av[e]);
            ah[e]  = (short)hA;
            al_[e] = (short)f2bf(av[e] - bf2f(hA));
            const unsigned short hB = f2bf(bv[e]);
            bh[e]  = (short)hB;
            bl[e]  = (short)f2bf(bv[e] - bf2f(hB));
        }
        acc = __builtin_amdgcn_mfma_f32_16x16x32_bf16(ah,  bh, acc, 0, 0, 0);
        acc = __builtin_amdgcn_mfma_f32_16x16x32_bf16(ah,  bl, acc, 0, 0, 0);
        acc = __builtin_amdgcn_mfma_f32_16x16x32_bf16(al_, bh, acc, 0, 0, 0);
    }

    // D layout: col = lane&15 -> batch, row = quad*4+reg -> j (4 consecutive)
    const int bidx = w * 16 + mlo;
    float4 r;
    r.x = acc[0]; r.y = acc[1]; r.z = acc[2]; r.w = acc[3];
    *(float4*)(ws + (size_t)bidx * NROWS + j0 + quad * 4) = r;
}

// ---------------------------------------------------------------------------
// Kernel 2: MFMA fused kernel, OUTPUT-TRANSPOSED tiling: D[p][m].
// R5: forced MLP via ONE mega-asm pin.  R4's per-value keeps were separate
// volatile asms -> only ordered among themselves -> the scheduler legally
// emitted load/wait/keep chains (MLP=1, VGPR=48).  A SINGLE asm with all 29
// operands requires every loaded value live at one point: all 28 loads
// issue back-to-back, one collective vmcnt drain, MLP/wave = 28.
// Peak live ~65 data regs + addressing -> ~96-120 VGPR, fits the 128-reg
// cap of __launch_bounds__(256,4), no spill expected.
// ---------------------------------------------------------------------------
__global__ __launch_bounds__(256, 4) void vstm_main(
    const float* __restrict__ inputs, const float* __restrict__ state,
    const float* __restrict__ ws, float* __restrict__ out)
{
    __shared__ __align__(16) unsigned char smem[23296];
    unsigned short* const IGs = (unsigned short*)(smem);          // [64][40], phase A
    unsigned short* const Tt  = (unsigned short*)(smem);          // [128][72], overlays IGs
    unsigned short* const OGs = (unsigned short*)(smem + 18432);  // [32][72], persistent
    float*          const fs  = (float*)(smem + 23040);           // [64],     persistent

    const int tid  = threadIdx.x;
    const int b    = blockIdx.y;
    const int tile = blockIdx.x * TILE;
    const int w    = __builtin_amdgcn_readfirstlane(tid >> 6);
    const int l    = tid & 63;
    const int quad = l >> 4;
    const int mlo  = l & 15;

    // ================= load-issue block =====================================
    const float* g = ws + (size_t)b * NROWS;
    float fsv = g[tid & 63];
    f32x4 giv0 = *(const f32x4*)(g + 64 + tid * 4);
    f32x4 giv1 = *(const f32x4*)(g + 64 + 1024 + tid * 4);
    f32x4 gov0 = *(const f32x4*)(g + 2112 + tid * 4);
    f32x4 gov1 = *(const f32x4*)(g + 2112 + 1024 + tid * 4);

    const float* xb = inputs + (size_t)b * IN_CH * HW + tile + w * 32;
    float xf[2][8];
#pragma unroll
    for (int pc = 0; pc < 2; ++pc)
#pragma unroll
        for (int j = 0; j < 8; ++j)
            xf[pc][j] = xb[(size_t)(quad * 8 + j) * HW + pc * 16 + mlo];

    const float* stb = state + (size_t)b * NMAPS * HW + tile;
    f32x4 stv[4][2];
#pragma unroll
    for (int mc = 0; mc < 4; ++mc)
#pragma unroll
        for (int pc = 0; pc < 2; ++pc)
            stv[mc][pc] = *(const f32x4*)(stb + (size_t)(mc * 16 + mlo) * HW
                                          + w * 32 + pc * 16 + quad * 4);

    // ---- single materialization pin: every operand must be simultaneously
    //      live in VGPRs here -> no load may sink below; all issue above. ----
    asm volatile(""
        : "+v"(fsv),
          "+v"(giv0), "+v"(giv1), "+v"(gov0), "+v"(gov1),
          "+v"(xf[0][0]), "+v"(xf[0][1]), "+v"(xf[0][2]), "+v"(xf[0][3]),
          "+v"(xf[0][4]), "+v"(xf[0][5]), "+v"(xf[0][6]), "+v"(xf[0][7]),
          "+v"(xf[1][0]), "+v"(xf[1][1]), "+v"(xf[1][2]), "+v"(xf[1][3]),
          "+v"(xf[1][4]), "+v"(xf[1][5]), "+v"(xf[1][6]), "+v"(xf[1][7]),
          "+v"(stv[0][0]), "+v"(stv[0][1]), "+v"(stv[1][0]), "+v"(stv[1][1]),
          "+v"(stv[2][0]), "+v"(stv[2][1]), "+v"(stv[3][0]), "+v"(stv[3][1]));
    // ========================================================================

    // ---- stage gates to LDS ----
    if (tid < 64) fs[tid] = fsv;
    {
        const int e = tid * 4;                               // 0..1020
        bf4_t vi0 = { (short)f2bf(giv0[0]), (short)f2bf(giv0[1]),
                      (short)f2bf(giv0[2]), (short)f2bf(giv0[3]) };
        *(bf4_t*)&IGs[(e >> 5) * 40 + (e & 31)] = vi0;
        bf4_t vi1 = { (short)f2bf(giv1[0]), (short)f2bf(giv1[1]),
                      (short)f2bf(giv1[2]), (short)f2bf(giv1[3]) };
        *(bf4_t*)&IGs[((e + 1024) >> 5) * 40 + ((e + 1024) & 31)] = vi1;
        bf4_t vo0 = { (short)f2bf(gov0[0]), (short)f2bf(gov0[1]),
                      (short)f2bf(gov0[2]), (short)f2bf(gov0[3]) };
        *(bf4_t*)&OGs[(e >> 6) * 72 + (e & 63)] = vo0;
        bf4_t vo1 = { (short)f2bf(gov1[0]), (short)f2bf(gov1[1]),
                      (short)f2bf(gov1[2]), (short)f2bf(gov1[3]) };
        *(bf4_t*)&OGs[((e + 1024) >> 6) * 72 + ((e + 1024) & 63)] = vo1;
    }
    __syncthreads();                        // barrier 1: gates staged

    // ---- B-fragments (IG) from LDS ----
    bf8_t bg[4];
#pragma unroll
    for (int mc = 0; mc < 4; ++mc)
        bg[mc] = *(const bf8_t*)&IGs[(mc * 16 + mlo) * 40 + quad * 8];

    // ---- A-fragments from xf (register-only conversion) ----
    bf8_t af[2];
#pragma unroll
    for (int pc = 0; pc < 2; ++pc)
#pragma unroll
        for (int j = 0; j < 8; ++j)
            af[pc][j] = (short)f2bf(xf[pc][j]);

    __syncthreads();                        // barrier 2: IGs consumed -> Tt may overwrite

    // ---- Phase A: D[p][m], wave w owns p in [32w, 32w+32) ----
    f32x4 acc[2][4];
#pragma unroll
    for (int pc = 0; pc < 2; ++pc)
#pragma unroll
        for (int mc = 0; mc < 4; ++mc) {
            acc[pc][mc] = (f32x4){0.f, 0.f, 0.f, 0.f};
            acc[pc][mc] = __builtin_amdgcn_mfma_f32_16x16x32_bf16(
                af[pc], bg[mc], acc[pc][mc], 0, 0, 0);
        }

    // ---- epilogue: ns = acc + state*f (state already in regs), float4 I/O,
    //      tanh -> Tt[p][m] bf16 (wave-private rows) ----
    float* nsb = out + OUT0_SZ + (size_t)b * NMAPS * HW + tile;
#pragma unroll
    for (int mc = 0; mc < 4; ++mc) {
        const int m = mc * 16 + mlo;
        const float fgt = fs[m];
#pragma unroll
        for (int pc = 0; pc < 2; ++pc) {
            const int p0 = w * 32 + pc * 16 + quad * 4;
            const f32x4 st = stv[mc][pc];
            f32x4 ns;
            ns[0] = acc[pc][mc][0] + st[0] * fgt;
            ns[1] = acc[pc][mc][1] + st[1] * fgt;
            ns[2] = acc[pc][mc][2] + st[2] * fgt;
            ns[3] = acc[pc][mc][3] + st[3] * fgt;
            *(f32x4*)(nsb + (size_t)m * HW + p0) = ns;
            Tt[(p0 + 0) * 72 + m] = f2bf(fast_tanh(ns[0]));
            Tt[(p0 + 1) * 72 + m] = f2bf(fast_tanh(ns[1]));
            Tt[(p0 + 2) * 72 + m] = f2bf(fast_tanh(ns[2]));
            Tt[(p0 + 3) * 72 + m] = f2bf(fast_tanh(ns[3]));
        }
    }
    // no barrier: wave w reads only Tt rows it wrote

    // ---- Phase B: D[p][o] = T^T[p][m] x OG^T[m][o], K=64 -> 2 steps ----
    bf8_t ag[2][2], at[2][2];
#pragma unroll
    for (int oc = 0; oc < 2; ++oc)
#pragma unroll
        for (int ks = 0; ks < 2; ++ks)
            ag[oc][ks] = *(const bf8_t*)&OGs[(oc * 16 + mlo) * 72 + ks * 32 + quad * 8];
#pragma unroll
    for (int pc = 0; pc < 2; ++pc)
#pragma unroll
        for (int ks = 0; ks < 2; ++ks)
            at[pc][ks] = *(const bf8_t*)&Tt[(w * 32 + pc * 16 + mlo) * 72 + ks * 32 + quad * 8];

    f32x4 acc2[2][2];
#pragma unroll
    for (int pc = 0; pc < 2; ++pc)
#pragma unroll
        for (int oc = 0; oc < 2; ++oc) {
            acc2[pc][oc] = (f32x4){0.f, 0.f, 0.f, 0.f};
#pragma unroll
            for (int ks = 0; ks < 2; ++ks)
                acc2[pc][oc] = __builtin_amdgcn_mfma_f32_16x16x32_bf16(
                    at[pc][ks], ag[oc][ks], acc2[pc][oc], 0, 0, 0);
        }

    float* ob = out + (size_t)b * OUT_CH * HW + tile;
#pragma unroll
    for (int pc = 0; pc < 2; ++pc)
#pragma unroll
        for (int oc = 0; oc < 2; ++oc) {
            const int p0 = w * 32 + pc * 16 + quad * 4;
            const int o  = oc * 16 + mlo;
            f32x4 r;
            r[0] = acc2[pc][oc][0];
            r[1] = acc2[pc][oc][1];
            r[2] = acc2[pc][oc][2];
            r[3] = acc2[pc][oc][3];
            *(f32x4*)(ob + (size_t)o * HW + p0) = r;
        }
}

extern "C" void kernel_launch(void* const* d_in, const int* in_sizes, int n_in,
                              void* d_out, int out_size, void* d_ws, size_t ws_size,
                              hipStream_t stream) {
    const float* inputs   = (const float*)d_in[0];
    const float* state    = (const float*)d_in[1];
    const float* controls = (const float*)d_in[2];
    const float* W        = (const float*)d_in[3];
    float*       out      = (float*)d_out;
    float*       ws       = (float*)d_ws;

    ctrl_gemm<<<dim3(NROWS / 16), 256, 0, stream>>>(controls, W, ws);

    dim3 g2(HW / TILE, B_SZ);
    vstm_main<<<g2, 256, 0, stream>>>(inputs, state, ws, out);
}